// Round 19
// baseline (64.596 us; speedup 1.0000x reference)
//
#include <hip/hip_runtime.h>
#include <math.h>

#define N_IMG 64
#define D_CH  128
#define P_PIX 4096
#define K_CL  32
#define S_SPL 8
#define P_BLK (P_PIX / S_SPL)   // 512 pixels per block
#define TP    64                // pixels per tile
#define N_TILE (P_BLK / TP)     // 8 tiles
#define XTS   264               // xT row stride (ushorts): 33 quads (odd -> uniform banks)
#define XDS   136               // xD row stride: 17 quads (odd)
#define APS   136               // a' row stride: 17 quads

typedef __attribute__((ext_vector_type(8))) short bf16x8;
typedef __attribute__((ext_vector_type(4))) float f32x4;

#define MFMA(a, b, c) __builtin_amdgcn_mfma_f32_16x16x32_bf16(a, b, c, 0, 0, 0)

// LDS-release barrier (no vmcnt drain): prefetch loads stay in flight.
#define BAR() do {                                            \
    asm volatile("s_waitcnt lgkmcnt(0)" ::: "memory");        \
    __builtin_amdgcn_s_barrier();                             \
} while (0)

// Truncation split: f = hi + lo (exact to 2^-17 rel); packed [hi4|lo4].
static __device__ __forceinline__ bf16x8 pack_hl(float a, float b, float c, float d) {
    unsigned ua = __float_as_uint(a), ub = __float_as_uint(b);
    unsigned uc = __float_as_uint(c), ud = __float_as_uint(d);
    float ra = a - __uint_as_float(ua & 0xffff0000u);
    float rb = b - __uint_as_float(ub & 0xffff0000u);
    float rc = c - __uint_as_float(uc & 0xffff0000u);
    float rd = d - __uint_as_float(ud & 0xffff0000u);
    bf16x8 r;
    r[0] = (short)(ua >> 16); r[1] = (short)(ub >> 16);
    r[2] = (short)(uc >> 16); r[3] = (short)(ud >> 16);
    r[4] = (short)(__float_as_uint(ra) >> 16);
    r[5] = (short)(__float_as_uint(rb) >> 16);
    r[6] = (short)(__float_as_uint(rc) >> 16);
    r[7] = (short)(__float_as_uint(rd) >> 16);
    return r;
}
// half-swap: [hi|lo] -> [lo|hi].  MFMA(A,B)+MFMA(swap(A),B) == exact full product.
static __device__ __forceinline__ bf16x8 swap_hl(bf16x8 v) {
    return __builtin_shufflevector(v, v, 4, 5, 6, 7, 0, 1, 2, 3);
}

// Layouts (ushort idx):
//  xT[p][kc*32 + q*8 + j]: p=0..63, slot=[hi(d=kc*16+4q+0..3)|lo]  (GEMM1 A rows)
//  xD[d][(pq)*8 + j]     : d=0..127, slot=[hi(x at p=4pq..+3)|lo]  (GEMM2 A rows)
//  ap[k][(pq)*8 + j]     : k=0..31,  slot=[hi(a' at p)|lo]          (GEMM2 B rows)
__global__ __launch_bounds__(256)
void netvlad_main(const float* __restrict__ x, const float* __restrict__ w,
                  float* __restrict__ aggp, float* __restrict__ asump)
{
    __shared__ __align__(16) ushort xT[64 * XTS];
    __shared__ __align__(16) ushort xD[128 * XDS];
    __shared__ __align__(16) ushort ap[K_CL * APS];
    __shared__ __align__(16) float  pbuf[64][4];
    __shared__ float asw[4][32];

    const int tid = threadIdx.x;
    const int n   = blockIdx.x >> 3;
    const int ps  = blockIdx.x & 7;

    const int l   = tid & 63;
    const int wid = tid >> 6;
    const int q   = l >> 4;
    const int ln  = l & 15;

    // ---- preload conv_w fragments, both k-halves, interleaved [hi|lo] ----
    bf16x8 wB[2][8];
    #pragma unroll
    for (int n2 = 0; n2 < 2; ++n2)
        #pragma unroll
        for (int kc = 0; kc < 8; ++kc) {
            float4 wv = *(const float4*)(w + (n2 * 16 + ln) * D_CH + kc * 16 + 4 * q);
            wB[n2][kc] = pack_hl(wv.x, wv.y, wv.z, wv.w);
        }

    f32x4 acc2[2][2];
    #pragma unroll
    for (int a = 0; a < 2; ++a)
        #pragma unroll
        for (int b = 0; b < 2; ++b)
            acc2[a][b] = (f32x4){0.f, 0.f, 0.f, 0.f};
    float asacc0 = 0.0f, asacc1 = 0.0f;

    const float* xin = x + (size_t)n * D_CH * P_PIX + ps * P_BLK;

    // register tiles: tv = 32 d at pixel l (for xT); xv = wave's 32-d slice, p-quads
    float  tv[32];
    float4 xv[8];

#define LOADT(tt) do {                                                        \
    const float* xt_ = xin + (tt) * TP;                                       \
    _Pragma("unroll")                                                         \
    for (int j_ = 0; j_ < 32; ++j_)                                           \
        tv[j_] = xt_[(size_t)(32 * wid + j_) * P_PIX + l];                    \
    _Pragma("unroll")                                                         \
    for (int it_ = 0; it_ < 8; ++it_)                                         \
        xv[it_] = *(const float4*)(xt_ +                                      \
            (size_t)(32 * wid + (l >> 4) + 4 * it_) * P_PIX + 4 * (l & 15));  \
} while (0)

#define STAGE() do {                                                          \
    _Pragma("unroll")                                                         \
    for (int s_ = 0; s_ < 8; ++s_) {                                          \
        int d0_ = 32 * wid + 4 * s_;                                          \
        int kc_ = d0_ >> 4, qq_ = (d0_ & 15) >> 2;                            \
        *(bf16x8*)&xT[l * XTS + kc_ * 32 + qq_ * 8] =                         \
            pack_hl(tv[4*s_], tv[4*s_+1], tv[4*s_+2], tv[4*s_+3]);            \
    }                                                                         \
    _Pragma("unroll")                                                         \
    for (int it_ = 0; it_ < 8; ++it_) {                                       \
        int d_ = 32 * wid + (l >> 4) + 4 * it_;                               \
        *(bf16x8*)&xD[d_ * XDS + (l & 15) * 8] =                              \
            pack_hl(xv[it_].x, xv[it_].y, xv[it_].z, xv[it_].w);              \
    }                                                                         \
    float sq_ = 0.f;                                                          \
    _Pragma("unroll")                                                         \
    for (int j_ = 0; j_ < 32; ++j_) sq_ += tv[j_] * tv[j_];                   \
    pbuf[l][wid] = sq_;                                                       \
} while (0)

    // ---- prologue: tile 0 staged; tile 1 prefetched ----
    LOADT(0);
    STAGE();
    LOADT(1);
    BAR();

    for (int t = 0; t < N_TILE; ++t) {
        // ============ phase A: GEMM1 + softmax + a' write ====================
        float sp[4];
        #pragma unroll
        for (int r = 0; r < 4; ++r) {
            float4 v4 = *(const float4*)&pbuf[16 * wid + 4 * q + r][0];
            sp[r] = 1.0f / fmaxf(sqrtf((v4.x + v4.y) + (v4.z + v4.w)), 1e-12f);
        }

        f32x4 acc1_0 = (f32x4){0.f, 0.f, 0.f, 0.f};
        f32x4 acc1_1 = (f32x4){0.f, 0.f, 0.f, 0.f};
        #pragma unroll
        for (int kc = 0; kc < 8; ++kc) {
            bf16x8 A = *(const bf16x8*)&xT[(16 * wid + ln) * XTS + kc * 32 + q * 8];
            bf16x8 As = swap_hl(A);
            acc1_0 = MFMA(A,  wB[0][kc], acc1_0);
            acc1_0 = MFMA(As, wB[0][kc], acc1_0);
            acc1_1 = MFMA(A,  wB[1][kc], acc1_1);
            acc1_1 = MFMA(As, wB[1][kc], acc1_1);
        }

        // in-wave softmax over k=32 (R10-verified pattern)
        float e0[4], e1[4], s[4];
        #pragma unroll
        for (int r = 0; r < 4; ++r) {
            e0[r] = __builtin_expf(acc1_0[r] * sp[r]);
            e1[r] = __builtin_expf(acc1_1[r] * sp[r]);
        }
        #pragma unroll
        for (int r = 0; r < 4; ++r) {
            s[r] = e0[r] + e1[r];
            s[r] += __shfl_xor(s[r], 1);
            s[r] += __shfl_xor(s[r], 2);
            s[r] += __shfl_xor(s[r], 4);
            s[r] += __shfl_xor(s[r], 8);
        }
        {
            float rt[4], sm0[4], sm1[4];
            #pragma unroll
            for (int r = 0; r < 4; ++r) rt[r] = __builtin_amdgcn_rcpf(s[r]);
            #pragma unroll
            for (int r = 0; r < 4; ++r) {
                sm0[r] = e0[r] * rt[r];
                sm1[r] = e1[r] * rt[r];
            }
            asacc0 += sm0[0] + sm0[1] + sm0[2] + sm0[3];
            asacc1 += sm1[0] + sm1[1] + sm1[2] + sm1[3];
            *(bf16x8*)&ap[ln * APS + (4 * wid + q) * 8] =
                pack_hl(sm0[0] * sp[0], sm0[1] * sp[1], sm0[2] * sp[2], sm0[3] * sp[3]);
            *(bf16x8*)&ap[(16 + ln) * APS + (4 * wid + q) * 8] =
                pack_hl(sm1[0] * sp[0], sm1[1] * sp[1], sm1[2] * sp[2], sm1[3] * sp[3]);
        }
        BAR();   // b1: a'(t) visible; xT reads done

        // ============ phase B1: GEMM2 (contract p=64, 4 chunks) ==============
        #pragma unroll
        for (int pc = 0; pc < 4; ++pc) {
            bf16x8 B0 = *(const bf16x8*)&ap[ln * APS + (pc * 4 + q) * 8];
            bf16x8 B1v = *(const bf16x8*)&ap[(16 + ln) * APS + (pc * 4 + q) * 8];
            bf16x8 A0 = *(const bf16x8*)&xD[(32 * wid + ln) * XDS + (pc * 4 + q) * 8];
            bf16x8 A1 = *(const bf16x8*)&xD[(32 * wid + 16 + ln) * XDS + (pc * 4 + q) * 8];
            bf16x8 A0s = swap_hl(A0), A1s = swap_hl(A1);
            acc2[0][0] = MFMA(A0,  B0,  acc2[0][0]);
            acc2[0][0] = MFMA(A0s, B0,  acc2[0][0]);
            acc2[0][1] = MFMA(A0,  B1v, acc2[0][1]);
            acc2[0][1] = MFMA(A0s, B1v, acc2[0][1]);
            acc2[1][0] = MFMA(A1,  B0,  acc2[1][0]);
            acc2[1][0] = MFMA(A1s, B0,  acc2[1][0]);
            acc2[1][1] = MFMA(A1,  B1v, acc2[1][1]);
            acc2[1][1] = MFMA(A1s, B1v, acc2[1][1]);
        }
        BAR();   // b2: xD/a'(t) reads done -> stage may overwrite

        // ============ phase B2: stage tile t+1, prefetch t+2 =================
        if (t + 1 < N_TILE) {
            STAGE();                       // tv/xv currently hold tile t+1
            if (t + 2 < N_TILE) LOADT(t + 2);
            BAR();   // b3: stage(t+1) visible for phase A(t+1)
        }
    }

    // ================= epilogue: partials to workspace (R10-verified) ========
    const int base = ((n * S_SPL + ps) * K_CL) * D_CH;
    #pragma unroll
    for (int m2 = 0; m2 < 2; ++m2)
        #pragma unroll
        for (int n2 = 0; n2 < 2; ++n2) {
            int k = n2 * 16 + ln;
            #pragma unroll
            for (int r = 0; r < 4; ++r) {
                int d = (2 * wid + m2) * 16 + 4 * q + r;
                aggp[base + k * D_CH + d] = acc2[m2][n2][r];
            }
        }
    asacc0 += __shfl_xor(asacc0, 16);
    asacc0 += __shfl_xor(asacc0, 32);
    asacc1 += __shfl_xor(asacc1, 16);
    asacc1 += __shfl_xor(asacc1, 32);
    if (l < 32) asw[wid][l] = (l < 16) ? asacc0 : asacc1;
    __syncthreads();
    if (tid < K_CL)
        asump[(n * S_SPL + ps) * K_CL + tid] =
            asw[0][tid] + asw[1][tid] + asw[2][tid] + asw[3][tid];
}

__global__ __launch_bounds__(256)
void netvlad_finish(const float* __restrict__ aggp, const float* __restrict__ asump,
                    const float* __restrict__ cen, float* __restrict__ out)
{
    __shared__ float red[K_CL][8];
    __shared__ float gw[4];
    __shared__ float gss;
    const int tid = threadIdx.x;
    const int n = blockIdx.x;
    const int k = tid >> 3;
    const int d0 = (tid & 7) << 4;

    float v[16];
    #pragma unroll
    for (int i = 0; i < 16; ++i) v[i] = 0.0f;
    float as = 0.0f;
    for (int qq = 0; qq < S_SPL; ++qq) {
        const float* src = aggp + (((n * S_SPL + qq) * K_CL) + k) * D_CH + d0;
        #pragma unroll
        for (int c = 0; c < 4; ++c) {
            float4 t4 = *(const float4*)(src + (c << 2));
            v[4*c+0] += t4.x; v[4*c+1] += t4.y; v[4*c+2] += t4.z; v[4*c+3] += t4.w;
        }
        as += asump[(n * S_SPL + qq) * K_CL + k];
    }
    const float* cp = cen + k * D_CH + d0;
    float ssq = 0.0f;
    #pragma unroll
    for (int c = 0; c < 4; ++c) {
        float4 c4 = *(const float4*)(cp + (c << 2));
        v[4*c+0] -= as * c4.x;
        v[4*c+1] -= as * c4.y;
        v[4*c+2] -= as * c4.z;
        v[4*c+3] -= as * c4.w;
    }
    #pragma unroll
    for (int i = 0; i < 16; ++i) ssq += v[i] * v[i];
    red[k][tid & 7] = ssq;
    __syncthreads();
    float s2 = 0.0f;
    #pragma unroll
    for (int j = 0; j < 8; ++j) s2 += red[k][j];
    const float sc1 = 1.0f / fmaxf(sqrtf(s2), 1e-12f);
    #pragma unroll
    for (int i = 0; i < 16; ++i) v[i] *= sc1;
    float g = ssq * sc1 * sc1;
    #pragma unroll
    for (int off = 1; off < 64; off <<= 1) g += __shfl_xor(g, off);
    if ((tid & 63) == 0) gw[tid >> 6] = g;
    __syncthreads();
    if (tid == 0) gss = 1.0f / fmaxf(sqrtf(gw[0] + gw[1] + gw[2] + gw[3]), 1e-12f);
    __syncthreads();
    const float gsc = gss;
    float* op = out + (size_t)n * (K_CL * D_CH) + k * D_CH + d0;
    #pragma unroll
    for (int c = 0; c < 4; ++c) {
        *(float4*)(op + (c << 2)) =
            make_float4(v[4*c+0]*gsc, v[4*c+1]*gsc, v[4*c+2]*gsc, v[4*c+3]*gsc);
    }
}

extern "C" void kernel_launch(void* const* d_in, const int* in_sizes, int n_in,
                              void* d_out, int out_size, void* d_ws, size_t ws_size,
                              hipStream_t stream)
{
    const float* x   = (const float*)d_in[0];
    const float* w   = (const float*)d_in[1];
    const float* cen = (const float*)d_in[2];
    float* out = (float*)d_out;

    float* aggp  = (float*)d_ws;                                    // [64][8][32][128] = 8 MB
    float* asump = aggp + (size_t)N_IMG * S_SPL * K_CL * D_CH;      // [64][8][32]

    netvlad_main<<<N_IMG * S_SPL, 256, 0, stream>>>(x, w, aggp, asump);
    netvlad_finish<<<N_IMG, 256, 0, stream>>>(aggp, asump, cen, out);
}

// Round 20
// 53.057 us; speedup vs baseline: 1.2175x; 1.2175x over previous
//
#include <hip/hip_runtime.h>
#include <math.h>

#define N_IMG 64
#define D_CH  128
#define P_PIX 4096
#define K_CL  32
#define S_SPL 8
#define P_BLK (P_PIX / S_SPL)   // 512 pixels per block
#define TP    32                // pixels per tile
#define N_TILE (P_BLK / TP)     // 16 tiles

typedef __attribute__((ext_vector_type(8))) short bf16x8;
typedef __attribute__((ext_vector_type(4))) float f32x4;

#define MFMA(a, b, c) __builtin_amdgcn_mfma_f32_16x16x32_bf16(a, b, c, 0, 0, 0)

// LDS-release barrier (no vmcnt drain): prefetch loads stay in flight.
#define BAR() do {                                            \
    asm volatile("s_waitcnt lgkmcnt(0)" ::: "memory");        \
    __builtin_amdgcn_s_barrier();                             \
} while (0)

// Truncation split: f = hi + lo + O(2^-17 |f|), hi/lo bf16.
static __device__ __forceinline__ void split4t(float a, float b, float c, float d,
                                               ushort4 &h, ushort4 &l) {
    unsigned ua = __float_as_uint(a), ub = __float_as_uint(b);
    unsigned uc = __float_as_uint(c), ud = __float_as_uint(d);
    h.x = (ushort)(ua >> 16); h.y = (ushort)(ub >> 16);
    h.z = (ushort)(uc >> 16); h.w = (ushort)(ud >> 16);
    float ra = a - __uint_as_float(ua & 0xffff0000u);
    float rb = b - __uint_as_float(ub & 0xffff0000u);
    float rc = c - __uint_as_float(uc & 0xffff0000u);
    float rd = d - __uint_as_float(ud & 0xffff0000u);
    l.x = (ushort)(__float_as_uint(ra) >> 16);
    l.y = (ushort)(__float_as_uint(rb) >> 16);
    l.z = (ushort)(__float_as_uint(rc) >> 16);
    l.w = (ushort)(__float_as_uint(rd) >> 16);
}

// Stage tile (tt) from regs (xv,tv) into xT + xD[(tt)&1] + pbuf,
// then prefetch regs for tile (tt)+1. Placed in GEMM2's phase (after b4),
// so its VALU/DS-writes/VMEM overlap GEMM2's DS-reads/MFMA.
#define STAGE_AND_PREFETCH(tt) do {                                          \
    const int cc_ = (tt) & 1;                                                \
    _Pragma("unroll")                                                        \
    for (int it = 0; it < 4; ++it) {                                         \
        int d_ = it * 32 + (tid >> 3);                                       \
        ushort4 h_, lo_;                                                     \
        split4t(xv[it].x, xv[it].y, xv[it].z, xv[it].w, h_, lo_);            \
        *(ushort4*)&xDh[cc_][d_ * 40 + 4 * (tid & 7)] = h_;                  \
        *(ushort4*)&xDl[cc_][d_ * 40 + 4 * (tid & 7)] = lo_;                 \
    }                                                                        \
    float sq_ = 0.f;                                                         \
    _Pragma("unroll")                                                        \
    for (int c_ = 0; c_ < 4; ++c_) {                                         \
        ushort4 h_, lo_;                                                     \
        split4t(tv[4*c_+0], tv[4*c_+1], tv[4*c_+2], tv[4*c_+3], h_, lo_);    \
        *(ushort4*)&xTh[pT * 136 + dbase + 4 * c_] = h_;                     \
        *(ushort4*)&xTl[pT * 136 + dbase + 4 * c_] = lo_;                    \
        sq_ += tv[4*c_+0]*tv[4*c_+0] + tv[4*c_+1]*tv[4*c_+1]                 \
             + tv[4*c_+2]*tv[4*c_+2] + tv[4*c_+3]*tv[4*c_+3];                \
    }                                                                        \
    sq_ += __shfl_xor(sq_, 32);                                              \
    if (l < 32) pbuf[wid][pT] = sq_;                                         \
    if ((tt) + 1 < N_TILE) {                                                 \
        const float* xt2_ = xin + ((tt) + 1) * TP;                           \
        _Pragma("unroll")                                                    \
        for (int it = 0; it < 4; ++it) {                                     \
            int d_ = it * 32 + (tid >> 3);                                   \
            xv[it] = *(const float4*)(xt2_ + d_ * P_PIX + 4 * (tid & 7));    \
        }                                                                    \
        _Pragma("unroll")                                                    \
        for (int j_ = 0; j_ < 16; ++j_)                                      \
            tv[j_] = xt2_[(size_t)(dbase + j_) * P_PIX + pT];                \
    }                                                                        \
} while (0)

__global__ __launch_bounds__(256)
void netvlad_main(const float* __restrict__ x, const float* __restrict__ w,
                  float* __restrict__ aggp, float* __restrict__ asump)
{
    __shared__ __align__(16) ushort xTh[32 * 136], xTl[32 * 136];
    __shared__ __align__(16) ushort xDh[2][128 * 40], xDl[2][128 * 40];
    __shared__ __align__(16) ushort aph[2][32 * 40],  apl[2][32 * 40];
    __shared__ __align__(16) float  xch[4][64][4];
    __shared__ float pbuf[4][32];   // per-wave ssq partials (pixel-indexed)
    __shared__ float asw[4][16];

    const int tid = threadIdx.x;
    const int n   = blockIdx.x >> 3;
    const int ps  = blockIdx.x & 7;

    const int l   = tid & 63;
    const int wid = tid >> 6;
    const int q   = l >> 4;       // 16-lane group
    const int ln  = l & 15;
    const int mt  = wid >> 1;     // GEMM1 pixel m-tile (0/1)
    const int nt  = wid & 1;      // GEMM1/2 k n-tile (0/1)

    // ---- preload conv_w fragments into registers (hi/lo bf16), per wave's nt ----
    bf16x8 wh[4], wl[4];
    #pragma unroll
    for (int kk = 0; kk < 4; ++kk) {
        const float* wp = w + (nt * 16 + ln) * D_CH + kk * 32 + 8 * q;
        float4 wa = *(const float4*)wp;
        float4 wb = *(const float4*)(wp + 4);
        ushort4 h1, l1, h2, l2;
        split4t(wa.x, wa.y, wa.z, wa.w, h1, l1);
        split4t(wb.x, wb.y, wb.z, wb.w, h2, l2);
        wh[kk][0] = (short)h1.x; wh[kk][1] = (short)h1.y; wh[kk][2] = (short)h1.z; wh[kk][3] = (short)h1.w;
        wh[kk][4] = (short)h2.x; wh[kk][5] = (short)h2.y; wh[kk][6] = (short)h2.z; wh[kk][7] = (short)h2.w;
        wl[kk][0] = (short)l1.x; wl[kk][1] = (short)l1.y; wl[kk][2] = (short)l1.z; wl[kk][3] = (short)l1.w;
        wl[kk][4] = (short)l2.x; wl[kk][5] = (short)l2.y; wl[kk][6] = (short)l2.z; wl[kk][7] = (short)l2.w;
    }

    f32x4 acc2[2][2];   // aggT accumulators: [m-subtile(d)][n-tile(k)]
    #pragma unroll
    for (int a = 0; a < 2; ++a)
        #pragma unroll
        for (int b = 0; b < 2; ++b)
            acc2[a][b] = (f32x4){0.f, 0.f, 0.f, 0.f};
    float asacc = 0.0f;

    const float* xin = x + (size_t)n * D_CH * P_PIX + ps * P_BLK;

    const int pT    = tid & 31;
    const int dbase = (tid >> 5) * 16;

    // ---- prologue: load tile 0 regs, stage(0), prefetch tile 1 ----
    float4 xv[4];
    float  tv[16];
    {
        const float* xt = xin;
        #pragma unroll
        for (int it = 0; it < 4; ++it) {
            int d = it * 32 + (tid >> 3);
            xv[it] = *(const float4*)(xt + d * P_PIX + 4 * (tid & 7));
        }
        #pragma unroll
        for (int j = 0; j < 16; ++j)
            tv[j] = xt[(size_t)(dbase + j) * P_PIX + pT];
    }
    STAGE_AND_PREFETCH(0);

    for (int t = 0; t < N_TILE; ++t) {
        const int c = t & 1;
        BAR();                                             // b1: stage(t) visible

        // ---- per-wave 1/||x||: all waves, in-register ----
        float spx, spy, spz, spw;
        {
            int pp = l & 31;
            int jb = (l >> 5) * 2;
            float vsq = pbuf[jb][pp] + pbuf[jb + 1][pp];
            vsq += __shfl_xor(vsq, 32);
            float sSl = 1.0f / fmaxf(sqrtf(vsq), 1e-12f);  // lane holds sS[p=l&31]
            int p0 = mt * 16 + 4 * q;
            spx = __shfl(sSl, p0 + 0);
            spy = __shfl(sSl, p0 + 1);
            spz = __shfl(sSl, p0 + 2);
            spw = __shfl(sSl, p0 + 3);
        }

        // ================= GEMM1: logits (p x k), contract d ==================
        f32x4 acc1 = (f32x4){0.f, 0.f, 0.f, 0.f};
        __builtin_amdgcn_s_setprio(1);   // T5: favor MFMA wave vs other block's VMEM
        #pragma unroll
        for (int kk = 0; kk < 4; ++kk) {
            int ia = (mt * 16 + ln) * 136 + kk * 32 + 8 * q;
            bf16x8 Ah = *(const bf16x8*)&xTh[ia];
            bf16x8 Al = *(const bf16x8*)&xTl[ia];
            acc1 = MFMA(Ah, wh[kk], acc1);
            acc1 = MFMA(Ah, wl[kk], acc1);
            acc1 = MFMA(Al, wh[kk], acc1);
        }
        __builtin_amdgcn_s_setprio(0);

        // ================= softmax over k (in-register, no max-sub) ===========
        float e[4], s[4];
        e[0] = __builtin_expf(acc1[0] * spx);
        e[1] = __builtin_expf(acc1[1] * spy);
        e[2] = __builtin_expf(acc1[2] * spz);
        e[3] = __builtin_expf(acc1[3] * spw);
        #pragma unroll
        for (int r = 0; r < 4; ++r) {
            s[r] = e[r];
            s[r] += __shfl_xor(s[r], 1);
            s[r] += __shfl_xor(s[r], 2);
            s[r] += __shfl_xor(s[r], 4);
            s[r] += __shfl_xor(s[r], 8);
        }
        *(float4*)&xch[wid][l][0] = make_float4(s[0], s[1], s[2], s[3]);
        BAR();                                             // b3: partial sums
        {
            float4 po = *(const float4*)&xch[wid ^ 1][l][0];
            float rt[4];
            rt[0] = __builtin_amdgcn_rcpf(s[0] + po.x);
            rt[1] = __builtin_amdgcn_rcpf(s[1] + po.y);
            rt[2] = __builtin_amdgcn_rcpf(s[2] + po.z);
            rt[3] = __builtin_amdgcn_rcpf(s[3] + po.w);
            float sm[4], ap[4];
            #pragma unroll
            for (int r = 0; r < 4; ++r) sm[r] = e[r] * rt[r];
            asacc += sm[0] + sm[1] + sm[2] + sm[3];
            ap[0] = sm[0] * spx; ap[1] = sm[1] * spy;
            ap[2] = sm[2] * spz; ap[3] = sm[3] * spw;
            ushort4 h, lo;
            split4t(ap[0], ap[1], ap[2], ap[3], h, lo);
            int ib = (nt * 16 + ln) * 40 + mt * 16 + 4 * q;
            *(ushort4*)&aph[c][ib] = h;
            *(ushort4*)&apl[c][ib] = lo;
        }
        BAR();                                             // b4: a'[c] visible;
                                                           //  xT/pbuf read-done

        // ====== GEMM2(t) on dbuf[c]  ||  stage(t+1) into dbuf[c^1] ============
        bf16x8 A2h[2], A2l[2], B2h[2], B2l[2];
        #pragma unroll
        for (int m2 = 0; m2 < 2; ++m2) {
            int ia = ((2 * wid + m2) * 16 + ln) * 40 + 8 * q;
            A2h[m2] = *(const bf16x8*)&xDh[c][ia];
            A2l[m2] = *(const bf16x8*)&xDl[c][ia];
        }
        #pragma unroll
        for (int n2 = 0; n2 < 2; ++n2) {
            int ib = (n2 * 16 + ln) * 40 + 8 * q;
            B2h[n2] = *(const bf16x8*)&aph[c][ib];
            B2l[n2] = *(const bf16x8*)&apl[c][ib];
        }
        __builtin_amdgcn_s_setprio(1);   // T5: MFMA cluster (pure-reg)
        #pragma unroll
        for (int m2 = 0; m2 < 2; ++m2)
            #pragma unroll
            for (int n2 = 0; n2 < 2; ++n2) {
                acc2[m2][n2] = MFMA(A2h[m2], B2h[n2], acc2[m2][n2]);
                acc2[m2][n2] = MFMA(A2h[m2], B2l[n2], acc2[m2][n2]);
                acc2[m2][n2] = MFMA(A2l[m2], B2h[n2], acc2[m2][n2]);
            }
        __builtin_amdgcn_s_setprio(0);
        if (t + 1 < N_TILE) {
            STAGE_AND_PREFETCH(t + 1);   // overlaps GEMM2's MFMA/DS-read shadow
        }
    }

    // ================= epilogue: partials to workspace =======================
    const int base = ((n * S_SPL + ps) * K_CL) * D_CH;
    #pragma unroll
    for (int m2 = 0; m2 < 2; ++m2)
        #pragma unroll
        for (int n2 = 0; n2 < 2; ++n2) {
            int k = n2 * 16 + ln;
            #pragma unroll
            for (int r = 0; r < 4; ++r) {
                int d = (2 * wid + m2) * 16 + 4 * q + r;
                aggp[base + k * D_CH + d] = acc2[m2][n2][r];
            }
        }
    asacc += __shfl_xor(asacc, 16);
    asacc += __shfl_xor(asacc, 32);
    if (l < 16) asw[wid][l] = asacc;
    __syncthreads();
    if (tid < K_CL)
        asump[(n * S_SPL + ps) * K_CL + tid] =
            asw[tid >> 4][tid & 15] + asw[(tid >> 4) + 2][tid & 15];
}

__global__ __launch_bounds__(256)
void netvlad_finish(const float* __restrict__ aggp, const float* __restrict__ asump,
                    const float* __restrict__ cen, float* __restrict__ out)
{
    __shared__ float red[K_CL][8];
    __shared__ float gw[4];
    __shared__ float gss;
    const int tid = threadIdx.x;
    const int n = blockIdx.x;
    const int k = tid >> 3;
    const int d0 = (tid & 7) << 4;

    float v[16];
    #pragma unroll
    for (int i = 0; i < 16; ++i) v[i] = 0.0f;
    float as = 0.0f;
    for (int qq = 0; qq < S_SPL; ++qq) {
        const float* src = aggp + (((n * S_SPL + qq) * K_CL) + k) * D_CH + d0;
        #pragma unroll
        for (int c = 0; c < 4; ++c) {
            float4 t4 = *(const float4*)(src + (c << 2));
            v[4*c+0] += t4.x; v[4*c+1] += t4.y; v[4*c+2] += t4.z; v[4*c+3] += t4.w;
        }
        as += asump[(n * S_SPL + qq) * K_CL + k];
    }
    const float* cp = cen + k * D_CH + d0;
    float ssq = 0.0f;
    #pragma unroll
    for (int c = 0; c < 4; ++c) {
        float4 c4 = *(const float4*)(cp + (c << 2));
        v[4*c+0] -= as * c4.x;
        v[4*c+1] -= as * c4.y;
        v[4*c+2] -= as * c4.z;
        v[4*c+3] -= as * c4.w;
    }
    #pragma unroll
    for (int i = 0; i < 16; ++i) ssq += v[i] * v[i];
    red[k][tid & 7] = ssq;
    __syncthreads();
    float s2 = 0.0f;
    #pragma unroll
    for (int j = 0; j < 8; ++j) s2 += red[k][j];
    const float sc1 = 1.0f / fmaxf(sqrtf(s2), 1e-12f);
    #pragma unroll
    for (int i = 0; i < 16; ++i) v[i] *= sc1;
    float g = ssq * sc1 * sc1;
    #pragma unroll
    for (int off = 1; off < 64; off <<= 1) g += __shfl_xor(g, off);
    if ((tid & 63) == 0) gw[tid >> 6] = g;
    __syncthreads();
    if (tid == 0) gss = 1.0f / fmaxf(sqrtf(gw[0] + gw[1] + gw[2] + gw[3]), 1e-12f);
    __syncthreads();
    const float gsc = gss;
    float* op = out + (size_t)n * (K_CL * D_CH) + k * D_CH + d0;
    #pragma unroll
    for (int c = 0; c < 4; ++c) {
        *(float4*)(op + (c << 2)) =
            make_float4(v[4*c+0]*gsc, v[4*c+1]*gsc, v[4*c+2]*gsc, v[4*c+3]*gsc);
    }
}

extern "C" void kernel_launch(void* const* d_in, const int* in_sizes, int n_in,
                              void* d_out, int out_size, void* d_ws, size_t ws_size,
                              hipStream_t stream)
{
    const float* x   = (const float*)d_in[0];
    const float* w   = (const float*)d_in[1];
    const float* cen = (const float*)d_in[2];
    float* out = (float*)d_out;

    float* aggp  = (float*)d_ws;                                    // [64][8][32][128] = 8 MB
    float* asump = aggp + (size_t)N_IMG * S_SPL * K_CL * D_CH;      // [64][8][32]

    netvlad_main<<<N_IMG * S_SPL, 256, 0, stream>>>(x, w, aggp, asump);
    netvlad_finish<<<N_IMG, 256, 0, stream>>>(aggp, asump, cen, out);
}